// Round 5
// baseline (609.175 us; speedup 1.0000x reference)
//
#include <hip/hip_runtime.h>
#include <stdint.h>

// Viterbi CRF decode: B=1024, T=1024, N=34 (32 tags + START=32 + END=33)
// One wave = one batch (1024 waves = 1024 SIMDs). Lane j<34 owns row j.
// Per step: 34 packed adds (v_pk_add_f32, bit-exact), max3 tree, exact
// first-index eq-scan. Score broadcast: 1 ds_write + 9 ds_read_b128.
// Backpointers packed 4 steps/word -> 1 ds_write_b32 per 4 steps.
#define BB 1024
#define TT 1024
#define NN 34
#define NEGV -6969.0f

typedef float v2f __attribute__((ext_vector_type(2)));
typedef float v4f __attribute__((ext_vector_type(4)));

__device__ __forceinline__ v2f pk_add(v2f a, v2f b) {
    v2f d;
    asm("v_pk_add_f32 %0, %1, %2" : "=v"(d) : "v"(a), "v"(b));
    return d;
}
__device__ __forceinline__ float rdlane_f(float v, int l) {
    return __int_as_float(__builtin_amdgcn_readlane(__float_as_int(v), l));
}
__device__ __forceinline__ float M3(float a, float b, float c) {
    return fmaxf(fmaxf(a, b), c);   // folds to v_max3_f32
}

__global__ __launch_bounds__(64, 1) void viterbi_wave(
        const float* __restrict__ feat,   // [B,T,34]
        const float* __restrict__ trans,  // [34,34]
        float* __restrict__ out)          // best[B] ++ path[B,T+1]
{
    __shared__ unsigned int bp32[256 * NN];        // packed bp, 34816 B
    __shared__ __align__(16) float sc[64];         // score exchange
    __shared__ unsigned char Fm[16 * NN];          // chunk maps

    const int lane = threadIdx.x;
    const int bg   = blockIdx.x;
    const int jc   = (lane < NN) ? lane : (NN - 1);

    // transition row as 17 float2 pairs (constant over t)
    v2f tr2[17];
#pragma unroll
    for (int p = 0; p < 17; ++p) {
        tr2[p].x = trans[jc * NN + 2 * p];
        tr2[p].y = trans[jc * NN + 2 * p + 1];
    }
    const float trE = trans[33 * NN + jc];

    const float* fpp = feat + (size_t)bg * TT * NN + jc;
    float fr0 = fpp[0 * NN], fr1 = fpp[1 * NN], fr2 = fpp[2 * NN], fr3 = fpp[3 * NN];

    // replicated score vector: 9 float4 (floats 0..35; 34,35 unused)
    v4f skv[9];
#pragma unroll
    for (int r = 0; r < 9; ++r) { skv[r].x = NEGV; skv[r].y = NEGV; skv[r].z = NEGV; skv[r].w = NEGV; }
    skv[8].x = 0.0f;   // float 32 = START

    float m = NEGV;

    auto vstep = [&](float f) -> int {
        v2f f2; f2.x = f; f2.y = f;
        v2f q2[17];
#pragma unroll
        for (int p = 0; p < 17; ++p) {
            v2f sp = (p & 1)
                ? __builtin_shufflevector(skv[p >> 1], skv[p >> 1], 2, 3)
                : __builtin_shufflevector(skv[p >> 1], skv[p >> 1], 0, 1);
            q2[p] = pk_add(pk_add(sp, f2), tr2[p]);   // exact: (s+f)+t
        }
        // 34-leaf max tree via max3 triples (exact)
        float t0  = M3(q2[0].x,  q2[0].y,  q2[1].x);
        float t1  = M3(q2[1].y,  q2[2].x,  q2[2].y);
        float t2  = M3(q2[3].x,  q2[3].y,  q2[4].x);
        float t3  = M3(q2[4].y,  q2[5].x,  q2[5].y);
        float t4  = M3(q2[6].x,  q2[6].y,  q2[7].x);
        float t5  = M3(q2[7].y,  q2[8].x,  q2[8].y);
        float t6  = M3(q2[9].x,  q2[9].y,  q2[10].x);
        float t7  = M3(q2[10].y, q2[11].x, q2[11].y);
        float t8  = M3(q2[12].x, q2[12].y, q2[13].x);
        float t9  = M3(q2[13].y, q2[14].x, q2[14].y);
        float t10 = M3(q2[15].x, q2[15].y, q2[16].x);
        float u0 = M3(t0, t1, t2);
        float u1 = M3(t3, t4, t5);
        float u2 = M3(t6, t7, t8);
        float u3 = M3(t9, t10, q2[16].y);
        float mx = fmaxf(fmaxf(u0, u1), fmaxf(u2, u3));

        // broadcast for next step: 1 write + 9 b128 broadcast reads
        sc[lane] = mx;
#pragma unroll
        for (int r = 0; r < 9; ++r) skv[r] = *(const v4f*)(&sc[4 * r]);

        // argmax = first k attaining mx: 4 descending cmp/sel chains + min
        int am0 = 255, am1 = 255, am2 = 255, am3 = 255;
#pragma unroll
        for (int k = 33; k >= 0; --k) {
            float vk = (k & 1) ? q2[k >> 1].y : q2[k >> 1].x;
            bool e = (vk == mx);
            if ((k & 3) == 0) am0 = e ? k : am0;
            else if ((k & 3) == 1) am1 = e ? k : am1;
            else if ((k & 3) == 2) am2 = e ? k : am2;
            else am3 = e ? k : am3;
        }
        m = mx;
        return min(min(am0, am1), min(am2, am3));
    };

    int wofs = lane;   // bp32 word index for this lane's group writes
    for (int n = 0; n < 255; ++n) {
        int a0, a1, a2, a3;
        { float f = fr0; fr0 = fpp[4 * NN]; a0 = vstep(f); }
        { float f = fr1; fr1 = fpp[5 * NN]; a1 = vstep(f); }
        { float f = fr2; fr2 = fpp[6 * NN]; a2 = vstep(f); }
        { float f = fr3; fr3 = fpp[7 * NN]; a3 = vstep(f); }
        unsigned u = (unsigned)a0 | ((unsigned)a1 << 8) |
                     ((unsigned)a2 << 16) | ((unsigned)a3 << 24);
        if (lane < NN) bp32[wofs] = u;
        wofs += NN;
        fpp += 4 * NN;
    }
    {   // epilogue group (t = 1020..1023)
        int a0 = vstep(fr0), a1 = vstep(fr1), a2 = vstep(fr2), a3 = vstep(fr3);
        unsigned u = (unsigned)a0 | ((unsigned)a1 << 8) |
                     ((unsigned)a2 << 16) | ((unsigned)a3 << 24);
        if (lane < NN) bp32[wofs] = u;
    }

    // ---- end transition + final max/argmax (uniform across lanes)
    float fs = m + trE;
    float bm = rdlane_f(fs, 0);
    int bi = 0;
#pragma unroll
    for (int k = 1; k < NN; ++k) {
        float v = rdlane_f(fs, k);
        bool g = (v > bm);                 // strict > => first index on ties
        bm = g ? v : bm;
        bi = g ? k : bi;
    }
    if (lane == 0) out[bg] = bm;

    // ---- backtrack on LDS (single wave: ds ops are wave-ordered)
    // byte(t, s) at (t>>2)*136 + s*4 + (t&3); chunk c spans 2176 B
    const unsigned char* bpb = (const unsigned char*)bp32;

    // level-1: 16 chunks x 34 hypotheses = 544 jobs; 9 jobs/lane
    int cc[9], xx[9], mm[9], cb[9];
#pragma unroll
    for (int r = 0; r < 9; ++r) {
        int job = 64 * r + lane;
        if (job > 543) job = 543;
        cc[r] = job / 34;
        xx[r] = job - 34 * cc[r];
        mm[r] = xx[r];
        cb[r] = cc[r] * 2176;
    }
    for (int i = 63; i >= 0; --i) {
        int ioff = ((i >> 2) * 136) + (i & 3);
#pragma unroll
        for (int r = 0; r < 9; ++r) mm[r] = bpb[cb[r] + ioff + 4 * mm[r]];
    }
#pragma unroll
    for (int r = 0; r < 9; ++r) Fm[cc[r] * NN + xx[r]] = (unsigned char)mm[r];

    // level-2: serial 16-chunk scan (uniform)
    int e = bi;
    int myeb = (lane == 15) ? e : 0;
#pragma unroll
    for (int c2 = 15; c2 >= 1; --c2) {
        e = Fm[c2 * NN + e];
        myeb = (lane == c2 - 1) ? e : myeb;
    }

    // emit: lanes 0..15 re-chase their chunk and write the path
    float* po = out + BB + (size_t)bg * (TT + 1);
    if (lane < 16) {
        int mm2 = myeb;
        int base = lane * 2176;
        for (int i = 63; i >= 0; --i) {
            mm2 = bpb[base + ((i >> 2) * 136) + (i & 3) + 4 * mm2];
            po[lane * 64 + i] = (float)mm2;
        }
    }
    if (lane == 16) po[TT] = (float)bi;
}

extern "C" void kernel_launch(void* const* d_in, const int* in_sizes, int n_in,
                              void* d_out, int out_size, void* d_ws, size_t ws_size,
                              hipStream_t stream) {
    const float* feat  = (const float*)d_in[0];   // [1024,1024,34]
    const float* trans = (const float*)d_in[1];   // [34,34]
    float* out = (float*)d_out;                   // 1024 + 1024*1025 floats
    (void)d_ws; (void)ws_size;

    viterbi_wave<<<BB, 64, 0, stream>>>(feat, trans, out);
}